// Round 5
// baseline (50517.065 us; speedup 1.0000x reference)
//
#include <hip/hip_runtime.h>
#include <cstdint>
#include <cstddef>

// ---------------------------------------------------------------------------
// QRNN 2-bit forward, exact ternary-integer formulation.
// flags[0]=1 -> floats are f32 (else bf16); flags[1]=1 -> text is int64.
// Ternary vectors (len 1024) bit-packed as 32 u64: [2i]=plus, [2i+1]=nonzero.
// As uint4 i: (p.lo, p.hi, z.lo, z.hi) for elements 64i..64i+63.
// dot: both=hz&wz; neg=both&(hp^wp); k=popc(both)-2*popc(neg)
// Decision v = k*0.1+bias vs +-0.5 is monotone in k -> precomputed integer
// thresholds kp/km reproduce the f64 predicate bit-exactly.
//
// R5: recurrence split 4 ways per batch (grid 256 = 4 quarters x 64 batches,
// quarter-major so a batch's quarters share an XCD under the %8 swizzle).
// h-piece exchange via device-scope atomics: per-wave RELEASE fetch_add on a
// monotone per-batch counter (16/step), ACQUIRE spin, ACQUIRE data loads.
// Parity-double-buffered slots: a writer at step t+1 proves all readers
// finished step t-1's slot, so overwrite is safe. Counters zeroed by the
// launch-prefix memset (ws is re-poisoned 0xAA before every timed launch).
// ---------------------------------------------------------------------------

static __device__ __forceinline__ float bf2f(unsigned short b) {
  return __uint_as_float(((unsigned)b) << 16);
}
static __device__ __forceinline__ unsigned short f2bf(float f) {
  unsigned u = __float_as_uint(f);
  u = (u + 0x7FFFu + ((u >> 16) & 1u)) >> 16;  // RNE
  return (unsigned short)u;
}
static __device__ __forceinline__ float loadw(const void* p, size_t i, int isf32) {
  return isf32 ? ((const float*)p)[i] : bf2f(((const unsigned short*)p)[i]);
}

__global__ __launch_bounds__(256) void k_detect(const unsigned short* __restrict__ embu,
                                                const int* __restrict__ text,
                                                int* __restrict__ flags) {
  int i = blockIdx.x * 256 + threadIdx.x;  // 65536 u16 samples: valid in either layout
  unsigned e = (embu[i] >> 7) & 0xFFu;     // bf16-view exponent field
  unsigned long long b = __ballot(e >= 127u);
  if ((threadIdx.x & 63) == 0 && b) atomicOr(&flags[0], 1);
  if (blockIdx.x == 0 && threadIdx.x == 0) {
    int allz = 1;
    for (int j = 0; j < 32; j++)
      if (text[2 * j + 1] != 0) allz = 0;   // first 256 B: valid in either layout
    flags[1] = allz;
  }
}

__global__ __launch_bounds__(256) void k_maxabs(const uint4* __restrict__ w,
                                                const int* __restrict__ flags,
                                                unsigned* __restrict__ out) {
  int isf32 = flags[0];
  int n16 = isf32 ? 7680000 : 3840000;  // 30720000 elems / (4 or 8 per uint4)
  float mf = 0.f;
  unsigned mb = 0;
  int i = blockIdx.x * blockDim.x + threadIdx.x;
  int stride = gridDim.x * blockDim.x;
  if (isf32) {
    for (; i < n16; i += stride) {
      uint4 v = w[i];
      mf = fmaxf(mf, fabsf(__uint_as_float(v.x)));
      mf = fmaxf(mf, fabsf(__uint_as_float(v.y)));
      mf = fmaxf(mf, fabsf(__uint_as_float(v.z)));
      mf = fmaxf(mf, fabsf(__uint_as_float(v.w)));
    }
  } else {
    for (; i < n16; i += stride) {
      uint4 v = w[i];
      unsigned a;
      a = v.x & 0x7FFF7FFFu; mb = max(mb, a & 0xFFFFu); mb = max(mb, a >> 16);
      a = v.y & 0x7FFF7FFFu; mb = max(mb, a & 0xFFFFu); mb = max(mb, a >> 16);
      a = v.z & 0x7FFF7FFFu; mb = max(mb, a & 0xFFFFu); mb = max(mb, a >> 16);
      a = v.w & 0x7FFF7FFFu; mb = max(mb, a & 0xFFFFu); mb = max(mb, a >> 16);
    }
    mf = bf2f((unsigned short)mb);
  }
  for (int off = 32; off > 0; off >>= 1) mf = fmaxf(mf, __shfl_down(mf, off));
  __shared__ float red[4];
  if ((threadIdx.x & 63) == 0) red[threadIdx.x >> 6] = mf;
  __syncthreads();
  if (threadIdx.x == 0) {
    float b = fmaxf(fmaxf(red[0], red[1]), fmaxf(red[2], red[3]));
    atomicMax(out, __float_as_uint(b));  // b >= 0: bit pattern order-monotone
  }
}

__global__ __launch_bounds__(1024) void k_tern_rows(
    const void* __restrict__ Wih, const void* __restrict__ Whh,
    const void* __restrict__ fcw, const int* __restrict__ flags,
    unsigned long long* __restrict__ wim, unsigned long long* __restrict__ whm,
    unsigned long long* __restrict__ fcm) {
  int isf32 = flags[0];
  int b = blockIdx.x;  // 0..4099
  const void* src;
  size_t rowoff;
  unsigned long long* dst;
  if (b < 2048)      { src = Wih; rowoff = (size_t)b * 1024; dst = wim + (size_t)b * 32; }
  else if (b < 4096) { int r = b - 2048; src = Whh; rowoff = (size_t)r * 1024; dst = whm + (size_t)r * 32; }
  else               { int r = b - 4096; src = fcw; rowoff = (size_t)r * 1024; dst = fcm + (size_t)r * 32; }
  double w = (double)loadw(src, rowoff + threadIdx.x, isf32);
  unsigned long long bp = __ballot(w > 0.05);   // THR*W_SCALE, exact f64
  unsigned long long bm = __ballot(w < -0.05);
  if ((threadIdx.x & 63) == 0) {
    int wv = threadIdx.x >> 6;
    dst[2 * wv] = bp;
    dst[2 * wv + 1] = bp | bm;
  }
}

__global__ __launch_bounds__(1024) void k_embed(const int* __restrict__ text,
    const void* __restrict__ emb, const int* __restrict__ flags,
    const unsigned* __restrict__ mab, unsigned long long* __restrict__ x0) {
  int isf32 = flags[0], i64 = flags[1];
  int bt = blockIdx.x;
  long long tok = i64 ? ((const long long*)text)[bt] : (long long)text[bt];
  double ma = (double)__uint_as_float(*mab);
  float s = (float)exp2(ceil(log2(ma)));           // pow-2 scale (int_max = 1)
  float inv_s = 1.0f / s;                          // exact (pow-2)
  float w = loadw(emb, (size_t)tok * 1024 + threadIdx.x, isf32);
  float q = rintf(w * inv_s);                      // exact mul, half-even
  q = fminf(fmaxf(q, -2.0f), 1.0f);                // clip [-2, 1] (bw = 2)
  float val = q * s;                               // exact
  int code = (val > 0.5f) ? 1 : ((val < -0.5f) ? -1 : 0);
  unsigned long long bp = __ballot(code == 1);
  unsigned long long bm = __ballot(code == -1);
  if ((threadIdx.x & 63) == 0) {
    int wv = threadIdx.x >> 6;
    x0[(size_t)bt * 32 + 2 * wv] = bp;
    x0[(size_t)bt * 32 + 2 * wv + 1] = bp | bm;
  }
}

// ---- bit-GEMM: n[bt][r] = <x_row[bt], Wi_row[r]> (integer) ----------------
__global__ __launch_bounds__(256, 4) void k_bitgemm(const unsigned long long* __restrict__ xm,
    const unsigned long long* __restrict__ wim, short* __restrict__ nbuf) {
  __shared__ __align__(16) uint4 lx[64 * 16];  // [bt][i] = (p.lo,p.hi,z.lo,z.hi)
  __shared__ unsigned any[64];
  int tid = threadIdx.x;
  int bt0 = blockIdx.x * 64;
  int r = blockIdx.y * 256 + tid;
  unsigned wplo[16], wphi[16], wzlo[16], wzhi[16];
  const uint4* wrow = (const uint4*)(wim + (size_t)r * 32);
#pragma unroll
  for (int i = 0; i < 16; i++) {
    uint4 w4 = wrow[i];
    wplo[i] = w4.x; wphi[i] = w4.y; wzlo[i] = w4.z; wzhi[i] = w4.w;
  }
  if (tid < 64) any[tid] = 0;
  __syncthreads();
  unsigned accor = 0;
#pragma unroll
  for (int i = 0; i < 4; i++) {
    int idx = tid * 4 + i;  // 0..1023 uint4 slots, straight copy
    uint4 v = ((const uint4*)(xm + (size_t)bt0 * 32))[idx];
    lx[idx] = v;
    accor |= v.z | v.w;  // nonzero-mask halves
  }
  if (accor) atomicOr(&any[tid >> 2], 1u);  // 4 threads per bt row
  __syncthreads();
  for (int bt = 0; bt < 64; bt++) {
    int k = 0;
    if (any[bt]) {
      const uint4* hx = lx + bt * 16;
      int sb = 0, sn = 0;
#pragma unroll
      for (int i = 0; i < 16; i++) {
        uint4 h = hx[i];  // broadcast ds_read_b128
        unsigned nzu = (unsigned)__builtin_amdgcn_readfirstlane((int)(h.z | h.w));
        if (nzu) {  // wave-uniform zero-word skip
          unsigned blo = h.z & wzlo[i];
          unsigned bhi = h.w & wzhi[i];
          unsigned nlo = (h.x ^ wplo[i]) & blo;
          unsigned nhi = (h.y ^ wphi[i]) & bhi;
          sb += __popc(blo) + __popc(bhi);
          sn += __popc(nlo) + __popc(nhi);
        }
      }
      k = sb - 2 * sn;
    }
    nbuf[(size_t)(bt0 + bt) * 1024 + r] = (short)k;
  }
}

// ---- 4-way split persistent recurrence ------------------------------------
// grid 256 = quarter-major (blk = q*64 + b). Block handles rows q*256..+255.
// Per step: 256-row dot (1 wave/SIMD), per-wave ballots -> 64-bit pieces,
// device-scope exchange, one __syncthreads.
__global__ __launch_bounds__(256, 1) void k_recur4(const short* __restrict__ nbuf,
    const unsigned long long* __restrict__ whm,
    const void* __restrict__ bih, const void* __restrict__ bhh,
    const int* __restrict__ flags, int layer,
    unsigned long long* __restrict__ xout, unsigned long long* __restrict__ hidm,
    unsigned long long* __restrict__ xgp, unsigned long long* __restrict__ xgz,
    unsigned* __restrict__ cnt) {
  int isf32 = flags[0];
  int blk = blockIdx.x;
  int b = blk & 63, q = blk >> 6;
  int tid = threadIdx.x;
  int r = q * 256 + tid;
  int wv = tid >> 6;
  int g = q * 4 + wv;          // my wave's global 64-row word index (0..15)
  int lane = tid & 63;

  unsigned wplo[16], wphi[16], wzlo[16], wzhi[16];
  const uint4* wrow = (const uint4*)(whm + (size_t)r * 32);
#pragma unroll
  for (int i = 0; i < 16; i++) {
    uint4 w4 = wrow[i];
    wplo[i] = w4.x; wphi[i] = w4.y; wzlo[i] = w4.z; wzhi[i] = w4.w;
  }
  size_t boff = (size_t)layer * 1024 + r;
  double bias = (double)loadw(bih, boff, isf32) + (double)loadw(bhh, boff, isf32);
  int kp = (int)ceil((0.5 - bias) * 10.0);
  while ((double)kp * 0.1 + bias <= 0.5) kp++;
  while ((double)(kp - 1) * 0.1 + bias > 0.5) kp--;
  int km = (int)floor((-0.5 - bias) * 10.0);
  while ((double)km * 0.1 + bias >= -0.5) km--;
  while ((double)(km + 1) * 0.1 + bias < -0.5) km++;

  __shared__ __align__(16) uint4 Hloc[2][16];
  if (tid < 32) ((unsigned long long*)Hloc)[tid] = 0;  // zero parity-0 slot
  __syncthreads();

  const short* nrow = nbuf + (size_t)b * 512 * 1024 + r;
  unsigned long long* xrow = xout ? xout + (size_t)b * 512 * 32 : (unsigned long long*)0;
  int nin = (int)nrow[0];
  int pb = 0;
  unsigned long long bp = 0, bz = 0;
  for (int t = 0; t < 512; t++) {
    uint4 h[16];
    const uint4* Hq = Hloc[pb];
#pragma unroll
    for (int i = 0; i < 16; i++) h[i] = Hq[i];   // 16 broadcast ds_read_b128
    int sb = 0, sn = 0;
#pragma unroll
    for (int i = 0; i < 16; i++) {
      unsigned nzu = (unsigned)__builtin_amdgcn_readfirstlane((int)(h[i].z | h[i].w));
      if (nzu) {  // wave-uniform zero-word skip
        unsigned blo = h[i].z & wzlo[i];
        unsigned bhi = h[i].w & wzhi[i];
        unsigned nlo = (h[i].x ^ wplo[i]) & blo;
        unsigned nhi = (h[i].y ^ wphi[i]) & bhi;
        sb += __popc(blo) + __popc(bhi);
        sn += __popc(nlo) + __popc(nhi);
      }
    }
    int k = nin + sb - 2 * sn;
    int nin_next = (t < 511) ? (int)nrow[(size_t)(t + 1) * 1024] : 0;
    bp = __ballot(k >= kp);
    bz = bp | __ballot(k <= km);
    if (lane == 0 && xrow) {
      xrow[(size_t)t * 32 + 2 * g] = bp;
      xrow[(size_t)t * 32 + 2 * g + 1] = bz;
    }
    if (t < 511) {
      int np = pb ^ 1;
      size_t sbase = ((size_t)np * 64 + b) * 16;
      if (lane == 0) {
        __hip_atomic_store(&xgp[sbase + g], bp, __ATOMIC_RELAXED, __HIP_MEMORY_SCOPE_AGENT);
        __hip_atomic_store(&xgz[sbase + g], bz, __ATOMIC_RELAXED, __HIP_MEMORY_SCOPE_AGENT);
        // RELEASE add orders this wave's two stores; 16 adds/step/batch
        __hip_atomic_fetch_add(&cnt[b], 1u, __ATOMIC_RELEASE, __HIP_MEMORY_SCOPE_AGENT);
      }
      unsigned tgt = 16u * (unsigned)(t + 1);
      if (lane == 0) {
        while (__hip_atomic_load(&cnt[b], __ATOMIC_ACQUIRE, __HIP_MEMORY_SCOPE_AGENT) < tgt) {}
      }
      if (lane < 4) {  // wave wv gathers words 4*wv..4*wv+3
        int j = wv * 4 + lane;
        unsigned long long pw = __hip_atomic_load(&xgp[sbase + j], __ATOMIC_ACQUIRE, __HIP_MEMORY_SCOPE_AGENT);
        unsigned long long zw = __hip_atomic_load(&xgz[sbase + j], __ATOMIC_ACQUIRE, __HIP_MEMORY_SCOPE_AGENT);
        uint4 o;
        o.x = (unsigned)pw; o.y = (unsigned)(pw >> 32);
        o.z = (unsigned)zw; o.w = (unsigned)(zw >> 32);
        Hloc[np][j] = o;
      }
      __syncthreads();
    }
    pb ^= 1;
    nin = nin_next;
  }
  if (lane == 0) {  // final h piece (word g) straight to hidm
    hidm[b * 32 + 2 * g] = bp;
    hidm[b * 32 + 2 * g + 1] = bz;
  }
}

__global__ __launch_bounds__(64) void k_fc(const unsigned long long* __restrict__ hidm,
    const unsigned long long* __restrict__ fcm, const int* __restrict__ flags,
    void* __restrict__ out) {
  int isf32 = flags[0];
  int lb = blockIdx.x, lane = threadIdx.x;
  unsigned long long hp = 0, hz = 0;
  if (lane < 16) {
    hp = hidm[lb * 32 + 2 * lane];
    hz = hidm[lb * 32 + 2 * lane + 1];
  }
#pragma unroll
  for (int o = 0; o < 4; o++) {
    int k = 0;
    if (lane < 16) {
      unsigned long long wp = fcm[o * 32 + 2 * lane], wz = fcm[o * 32 + 2 * lane + 1];
      unsigned long long both = hz & wz;
      unsigned long long neg = both & (hp ^ wp);
      k = __popcll(both) - 2 * __popcll(neg);
    }
    for (int off = 8; off > 0; off >>= 1) k += __shfl_down(k, off);
    if (lane == 0) {
      float v = (float)((double)k * 0.1);
      if (isf32) ((float*)out)[lb * 4 + o] = v;
      else       ((unsigned short*)out)[lb * 4 + o] = f2bf(v);
    }
  }
}

extern "C" void kernel_launch(void* const* d_in, const int* in_sizes, int n_in,
                              void* d_out, int out_size, void* d_ws, size_t ws_size,
                              hipStream_t stream) {
  (void)in_sizes; (void)n_in; (void)out_size; (void)ws_size;
  const int* text = (const int*)d_in[0];
  // d_in[1] text_lengths: unused by the reference
  const void* emb = d_in[2];
  const void* Wih = d_in[3];
  const void* Whh = d_in[4];
  const void* bih = d_in[5];
  const void* bhh = d_in[6];
  const void* fcw = d_in[7];

  // workspace layout (~73 MB)
  char* ws = (char*)d_ws;
  int* flags = (int*)(ws);
  unsigned* mab = (unsigned*)(ws + 64);
  unsigned* cnt = (unsigned*)(ws + 128);                     // 128 u32 (64/layer)
  unsigned long long* xgp = (unsigned long long*)(ws + 4096);   // [2][64][16]
  unsigned long long* xgz = (unsigned long long*)(ws + 20480);  // [2][64][16]
  size_t off = 40960;
  unsigned long long* x0 = (unsigned long long*)(ws + off);  off += (size_t)32768 * 256;
  unsigned long long* wim = (unsigned long long*)(ws + off); off += (size_t)2048 * 256;
  unsigned long long* whm = (unsigned long long*)(ws + off); off += (size_t)2048 * 256;
  unsigned long long* fcm = (unsigned long long*)(ws + off); off += (size_t)4 * 256;
  unsigned long long* hidm = (unsigned long long*)(ws + off); off += (size_t)128 * 256;
  short* nbuf = (short*)(ws + off);                          off += (size_t)32768 * 1024 * 2;

  hipMemsetAsync(ws, 0, 4096, stream);  // flags + mab + cnt
  k_detect<<<256, 256, 0, stream>>>((const unsigned short*)emb, text, flags);
  k_maxabs<<<2048, 256, 0, stream>>>((const uint4*)emb, flags, mab);
  k_tern_rows<<<4100, 1024, 0, stream>>>(Wih, Whh, fcw, flags, wim, whm, fcm);
  k_embed<<<32768, 1024, 0, stream>>>(text, emb, flags, mab, x0);
  // layer 0: x0 -> nbuf -> recurrence -> x0 (x0 dead after bitgemm)
  k_bitgemm<<<dim3(512, 4), 256, 0, stream>>>(x0, wim, nbuf);
  k_recur4<<<256, 256, 0, stream>>>(nbuf, whm, bih, bhh, flags, 0, x0, hidm,
                                    xgp, xgz, cnt);
  // layer 1
  k_bitgemm<<<dim3(512, 4), 256, 0, stream>>>(x0, wim + (size_t)1024 * 32, nbuf);
  k_recur4<<<256, 256, 0, stream>>>(nbuf, whm + (size_t)1024 * 32, bih, bhh, flags, 1,
                                    (unsigned long long*)0, hidm + 64 * 32,
                                    xgp, xgz, cnt + 64);
  k_fc<<<128, 64, 0, stream>>>(hidm, fcm, flags, d_out);
}

// Round 6
// 2434.109 us; speedup vs baseline: 20.7538x; 20.7538x over previous
//
#include <hip/hip_runtime.h>
#include <cstdint>
#include <cstddef>

// ---------------------------------------------------------------------------
// QRNN 2-bit forward, exact ternary-integer formulation.
// flags[0]=1 -> floats are f32 (else bf16); flags[1]=1 -> text is int64.
// Ternary vectors (len 1024) bit-packed as 32 u64: [2i]=plus, [2i+1]=nonzero.
// As uint4 i: (p.lo, p.hi, z.lo, z.hi) for elements 64i..64i+63.
// dot: both=hz&wz; neg=both&(hp^wp); k=popc(both)-2*popc(neg)
// Decision v = k*0.1+bias vs +-0.5 is monotone in k -> integer thresholds
// kp/km reproduce the f64 predicate bit-exactly.
//
// R6: single-CU-per-batch recurrence (R5's cross-CU exchange was 30-60x
// slower: per-step device-scope sync costs ~50us). New: h is provably sparse
// (P(|bias|>0.5)~4e-4, inputs near-empty), so the step dot skips zero
// h-words via a 16-byte nonzero bitmap in LDS -> scalar s_cbranch skips,
// no LDS load and no popcount group for zero words.
// ---------------------------------------------------------------------------

static __device__ __forceinline__ float bf2f(unsigned short b) {
  return __uint_as_float(((unsigned)b) << 16);
}
static __device__ __forceinline__ unsigned short f2bf(float f) {
  unsigned u = __float_as_uint(f);
  u = (u + 0x7FFFu + ((u >> 16) & 1u)) >> 16;  // RNE
  return (unsigned short)u;
}
static __device__ __forceinline__ float loadw(const void* p, size_t i, int isf32) {
  return isf32 ? ((const float*)p)[i] : bf2f(((const unsigned short*)p)[i]);
}

__global__ __launch_bounds__(256) void k_detect(const unsigned short* __restrict__ embu,
                                                const int* __restrict__ text,
                                                int* __restrict__ flags) {
  int i = blockIdx.x * 256 + threadIdx.x;  // 65536 u16 samples: valid in either layout
  unsigned e = (embu[i] >> 7) & 0xFFu;     // bf16-view exponent field
  unsigned long long b = __ballot(e >= 127u);
  if ((threadIdx.x & 63) == 0 && b) atomicOr(&flags[0], 1);
  if (blockIdx.x == 0 && threadIdx.x == 0) {
    int allz = 1;
    for (int j = 0; j < 32; j++)
      if (text[2 * j + 1] != 0) allz = 0;   // first 256 B: valid in either layout
    flags[1] = allz;
  }
}

__global__ __launch_bounds__(256) void k_maxabs(const uint4* __restrict__ w,
                                                const int* __restrict__ flags,
                                                unsigned* __restrict__ out) {
  int isf32 = flags[0];
  int n16 = isf32 ? 7680000 : 3840000;  // 30720000 elems / (4 or 8 per uint4)
  float mf = 0.f;
  unsigned mb = 0;
  int i = blockIdx.x * blockDim.x + threadIdx.x;
  int stride = gridDim.x * blockDim.x;
  if (isf32) {
    for (; i < n16; i += stride) {
      uint4 v = w[i];
      mf = fmaxf(mf, fabsf(__uint_as_float(v.x)));
      mf = fmaxf(mf, fabsf(__uint_as_float(v.y)));
      mf = fmaxf(mf, fabsf(__uint_as_float(v.z)));
      mf = fmaxf(mf, fabsf(__uint_as_float(v.w)));
    }
  } else {
    for (; i < n16; i += stride) {
      uint4 v = w[i];
      unsigned a;
      a = v.x & 0x7FFF7FFFu; mb = max(mb, a & 0xFFFFu); mb = max(mb, a >> 16);
      a = v.y & 0x7FFF7FFFu; mb = max(mb, a & 0xFFFFu); mb = max(mb, a >> 16);
      a = v.z & 0x7FFF7FFFu; mb = max(mb, a & 0xFFFFu); mb = max(mb, a >> 16);
      a = v.w & 0x7FFF7FFFu; mb = max(mb, a & 0xFFFFu); mb = max(mb, a >> 16);
    }
    mf = bf2f((unsigned short)mb);
  }
  for (int off = 32; off > 0; off >>= 1) mf = fmaxf(mf, __shfl_down(mf, off));
  __shared__ float red[4];
  if ((threadIdx.x & 63) == 0) red[threadIdx.x >> 6] = mf;
  __syncthreads();
  if (threadIdx.x == 0) {
    float b = fmaxf(fmaxf(red[0], red[1]), fmaxf(red[2], red[3]));
    atomicMax(out, __float_as_uint(b));  // b >= 0: bit pattern order-monotone
  }
}

__global__ __launch_bounds__(1024) void k_tern_rows(
    const void* __restrict__ Wih, const void* __restrict__ Whh,
    const void* __restrict__ fcw, const int* __restrict__ flags,
    unsigned long long* __restrict__ wim, unsigned long long* __restrict__ whm,
    unsigned long long* __restrict__ fcm) {
  int isf32 = flags[0];
  int b = blockIdx.x;  // 0..4099
  const void* src;
  size_t rowoff;
  unsigned long long* dst;
  if (b < 2048)      { src = Wih; rowoff = (size_t)b * 1024; dst = wim + (size_t)b * 32; }
  else if (b < 4096) { int r = b - 2048; src = Whh; rowoff = (size_t)r * 1024; dst = whm + (size_t)r * 32; }
  else               { int r = b - 4096; src = fcw; rowoff = (size_t)r * 1024; dst = fcm + (size_t)r * 32; }
  double w = (double)loadw(src, rowoff + threadIdx.x, isf32);
  unsigned long long bp = __ballot(w > 0.05);   // THR*W_SCALE, exact f64
  unsigned long long bm = __ballot(w < -0.05);
  if ((threadIdx.x & 63) == 0) {
    int wv = threadIdx.x >> 6;
    dst[2 * wv] = bp;
    dst[2 * wv + 1] = bp | bm;
  }
}

__global__ __launch_bounds__(1024) void k_embed(const int* __restrict__ text,
    const void* __restrict__ emb, const int* __restrict__ flags,
    const unsigned* __restrict__ mab, unsigned long long* __restrict__ x0) {
  int isf32 = flags[0], i64 = flags[1];
  int bt = blockIdx.x;
  long long tok = i64 ? ((const long long*)text)[bt] : (long long)text[bt];
  double ma = (double)__uint_as_float(*mab);
  float s = (float)exp2(ceil(log2(ma)));           // pow-2 scale (int_max = 1)
  float inv_s = 1.0f / s;                          // exact (pow-2)
  float w = loadw(emb, (size_t)tok * 1024 + threadIdx.x, isf32);
  float q = rintf(w * inv_s);                      // exact mul, half-even
  q = fminf(fmaxf(q, -2.0f), 1.0f);                // clip [-2, 1] (bw = 2)
  float val = q * s;                               // exact
  int code = (val > 0.5f) ? 1 : ((val < -0.5f) ? -1 : 0);
  unsigned long long bp = __ballot(code == 1);
  unsigned long long bm = __ballot(code == -1);
  if ((threadIdx.x & 63) == 0) {
    int wv = threadIdx.x >> 6;
    x0[(size_t)bt * 32 + 2 * wv] = bp;
    x0[(size_t)bt * 32 + 2 * wv + 1] = bp | bm;
  }
}

// ---- bit-GEMM: n[bt][r] = <x_row[bt], Wi_row[r]> (integer) ----------------
__global__ __launch_bounds__(256, 4) void k_bitgemm(const unsigned long long* __restrict__ xm,
    const unsigned long long* __restrict__ wim, short* __restrict__ nbuf) {
  __shared__ __align__(16) uint4 lx[64 * 16];  // [bt][i] = (p.lo,p.hi,z.lo,z.hi)
  __shared__ unsigned any[64];
  int tid = threadIdx.x;
  int bt0 = blockIdx.x * 64;
  int r = blockIdx.y * 256 + tid;
  unsigned wplo[16], wphi[16], wzlo[16], wzhi[16];
  const uint4* wrow = (const uint4*)(wim + (size_t)r * 32);
#pragma unroll
  for (int i = 0; i < 16; i++) {
    uint4 w4 = wrow[i];
    wplo[i] = w4.x; wphi[i] = w4.y; wzlo[i] = w4.z; wzhi[i] = w4.w;
  }
  if (tid < 64) any[tid] = 0;
  __syncthreads();
  unsigned accor = 0;
#pragma unroll
  for (int i = 0; i < 4; i++) {
    int idx = tid * 4 + i;  // 0..1023 uint4 slots, straight copy
    uint4 v = ((const uint4*)(xm + (size_t)bt0 * 32))[idx];
    lx[idx] = v;
    accor |= v.z | v.w;  // nonzero-mask halves
  }
  if (accor) atomicOr(&any[tid >> 2], 1u);  // 4 threads per bt row
  __syncthreads();
  for (int bt = 0; bt < 64; bt++) {
    int k = 0;
    if (any[bt]) {
      const uint4* hx = lx + bt * 16;
      int sb = 0, sn = 0;
#pragma unroll
      for (int i = 0; i < 16; i++) {
        uint4 h = hx[i];  // broadcast ds_read_b128
        unsigned nzu = (unsigned)__builtin_amdgcn_readfirstlane((int)(h.z | h.w));
        if (nzu) {  // wave-uniform zero-word skip
          unsigned blo = h.z & wzlo[i];
          unsigned bhi = h.w & wzhi[i];
          unsigned nlo = (h.x ^ wplo[i]) & blo;
          unsigned nhi = (h.y ^ wphi[i]) & bhi;
          sb += __popc(blo) + __popc(bhi);
          sn += __popc(nlo) + __popc(nhi);
        }
      }
      k = sb - 2 * sn;
    }
    nbuf[(size_t)(bt0 + bt) * 1024 + r] = (short)k;
  }
}

// ---- persistent recurrence (single CU per batch) --------------------------
// 1024 threads, thread = output row. Per step:
//   - 16-byte word-nonzero bitmap (broadcast ds_read_b128 + readfirstlane)
//   - scalar-branch skip per h-word: zero words cost 0 LDS loads, 0 VALU
//   - integer-threshold decision; single barrier (parity double buffer)
__global__ __launch_bounds__(1024, 4) void k_recur(const short* __restrict__ nbuf,
    const unsigned long long* __restrict__ whm,
    const void* __restrict__ bih, const void* __restrict__ bhh,
    const int* __restrict__ flags, int layer,
    unsigned long long* __restrict__ xout, unsigned long long* __restrict__ hidm) {
  int isf32 = flags[0];
  int b = blockIdx.x, r = threadIdx.x;
  unsigned wplo[16], wphi[16], wzlo[16], wzhi[16];
  const uint4* wrow = (const uint4*)(whm + (size_t)r * 32);
#pragma unroll
  for (int i = 0; i < 16; i++) {
    uint4 w4 = wrow[i];
    wplo[i] = w4.x; wphi[i] = w4.y; wzlo[i] = w4.z; wzhi[i] = w4.w;
  }
  size_t boff = (size_t)layer * 1024 + r;
  double bias = (double)loadw(bih, boff, isf32) + (double)loadw(bhh, boff, isf32);
  // exact integer thresholds reproducing the f64 predicate
  int kp = (int)ceil((0.5 - bias) * 10.0);
  while ((double)kp * 0.1 + bias <= 0.5) kp++;
  while ((double)(kp - 1) * 0.1 + bias > 0.5) kp--;
  int km = (int)floor((-0.5 - bias) * 10.0);
  while ((double)km * 0.1 + bias >= -0.5) km--;
  while ((double)(km + 1) * 0.1 + bias < -0.5) km++;

  __shared__ __align__(16) uint4 Hbuf[2][16];   // (p.lo,p.hi,z.lo,z.hi)
  __shared__ __align__(16) unsigned nzb[2][4];  // byte w = (word w nonzero)
  if (r < 32) ((unsigned long long*)Hbuf)[r] = 0;  // zero parity-0 H
  if (r < 4) nzb[0][r] = 0;
  __syncthreads();
  const short* nrow = nbuf + (size_t)b * 512 * 1024 + r;
  unsigned long long* xrow = xout ? xout + (size_t)b * 512 * 32 : (unsigned long long*)0;
  int wv = r >> 6;
  bool l0 = (r & 63) == 0;
  int nin = (int)nrow[0];  // t = 0 preload
  int pb = 0;
  unsigned long long bp = 0, bz = 0;
  for (int t = 0; t < 512; t++) {
    const uint4* Hq = Hbuf[pb];
    uint4 m4 = *(const uint4*)&nzb[pb][0];  // broadcast; bytes = word-nonzero flags
    unsigned m0 = (unsigned)__builtin_amdgcn_readfirstlane((int)m4.x);
    unsigned m1 = (unsigned)__builtin_amdgcn_readfirstlane((int)m4.y);
    unsigned m2 = (unsigned)__builtin_amdgcn_readfirstlane((int)m4.z);
    unsigned m3 = (unsigned)__builtin_amdgcn_readfirstlane((int)m4.w);
    int sb = 0, sn = 0;
#pragma unroll
    for (int i = 0; i < 16; i++) {
      unsigned mw = (i < 4) ? m0 : (i < 8) ? m1 : (i < 12) ? m2 : m3;
      if ((mw >> (8 * (i & 3))) & 0xFFu) {  // scalar s_cbranch: skip zero word
        uint4 h = Hq[i];  // broadcast ds_read_b128 (only for nonzero words)
        unsigned blo = h.z & wzlo[i];
        unsigned bhi = h.w & wzhi[i];
        unsigned nlo = (h.x ^ wplo[i]) & blo;
        unsigned nhi = (h.y ^ wphi[i]) & bhi;
        sb += __popc(blo) + __popc(bhi);
        sn += __popc(nlo) + __popc(nhi);
      }
    }
    int k = nin + sb - 2 * sn;
    int nin_next = (t < 511) ? (int)nrow[(size_t)(t + 1) * 1024] : 0;  // prefetch
    bp = __ballot(k >= kp);
    bz = bp | __ballot(k <= km);
    if (l0) {
      int np = pb ^ 1;
      uint4 o;
      o.x = (unsigned)bp; o.y = (unsigned)(bp >> 32);
      o.z = (unsigned)bz; o.w = (unsigned)(bz >> 32);
      Hbuf[np][wv] = o;
      ((unsigned char*)&nzb[np][0])[wv] = bz ? 1u : 0u;
      if (xrow) ((uint4*)(xrow + (size_t)t * 32))[wv] = o;
    }
    __syncthreads();  // writes of parity np visible; reads of parity pb done
    pb ^= 1;
    nin = nin_next;
  }
  if (l0) {  // h after step 511 = this wave's last ballots
    hidm[b * 32 + 2 * wv] = bp;
    hidm[b * 32 + 2 * wv + 1] = bz;
  }
}

__global__ __launch_bounds__(64) void k_fc(const unsigned long long* __restrict__ hidm,
    const unsigned long long* __restrict__ fcm, const int* __restrict__ flags,
    void* __restrict__ out) {
  int isf32 = flags[0];
  int lb = blockIdx.x, lane = threadIdx.x;
  unsigned long long hp = 0, hz = 0;
  if (lane < 16) {
    hp = hidm[lb * 32 + 2 * lane];
    hz = hidm[lb * 32 + 2 * lane + 1];
  }
#pragma unroll
  for (int o = 0; o < 4; o++) {
    int k = 0;
    if (lane < 16) {
      unsigned long long wp = fcm[o * 32 + 2 * lane], wz = fcm[o * 32 + 2 * lane + 1];
      unsigned long long both = hz & wz;
      unsigned long long neg = both & (hp ^ wp);
      k = __popcll(both) - 2 * __popcll(neg);
    }
    for (int off = 8; off > 0; off >>= 1) k += __shfl_down(k, off);
    if (lane == 0) {
      float v = (float)((double)k * 0.1);
      if (isf32) ((float*)out)[lb * 4 + o] = v;
      else       ((unsigned short*)out)[lb * 4 + o] = f2bf(v);
    }
  }
}

extern "C" void kernel_launch(void* const* d_in, const int* in_sizes, int n_in,
                              void* d_out, int out_size, void* d_ws, size_t ws_size,
                              hipStream_t stream) {
  (void)in_sizes; (void)n_in; (void)out_size; (void)ws_size;
  const int* text = (const int*)d_in[0];
  // d_in[1] text_lengths: unused by the reference
  const void* emb = d_in[2];
  const void* Wih = d_in[3];
  const void* Whh = d_in[4];
  const void* bih = d_in[5];
  const void* bhh = d_in[6];
  const void* fcw = d_in[7];

  // workspace layout (~73 MB)
  char* ws = (char*)d_ws;
  size_t off = 0;
  int* flags = (int*)(ws);
  unsigned* mab = (unsigned*)(ws + 64);                      off += 256;
  unsigned long long* x0 = (unsigned long long*)(ws + off);  off += (size_t)32768 * 256;
  unsigned long long* wim = (unsigned long long*)(ws + off); off += (size_t)2048 * 256;
  unsigned long long* whm = (unsigned long long*)(ws + off); off += (size_t)2048 * 256;
  unsigned long long* fcm = (unsigned long long*)(ws + off); off += (size_t)4 * 256;
  unsigned long long* hidm = (unsigned long long*)(ws + off); off += (size_t)128 * 256;
  short* nbuf = (short*)(ws + off);                          off += (size_t)32768 * 1024 * 2;

  hipMemsetAsync(ws, 0, 256, stream);
  k_detect<<<256, 256, 0, stream>>>((const unsigned short*)emb, text, flags);
  k_maxabs<<<2048, 256, 0, stream>>>((const uint4*)emb, flags, mab);
  k_tern_rows<<<4100, 1024, 0, stream>>>(Wih, Whh, fcw, flags, wim, whm, fcm);
  k_embed<<<32768, 1024, 0, stream>>>(text, emb, flags, mab, x0);
  // layer 0: x0 -> nbuf -> recurrence -> x0 (x0 dead after bitgemm)
  k_bitgemm<<<dim3(512, 4), 256, 0, stream>>>(x0, wim, nbuf);
  k_recur<<<64, 1024, 0, stream>>>(nbuf, whm, bih, bhh, flags, 0, x0, hidm);
  // layer 1
  k_bitgemm<<<dim3(512, 4), 256, 0, stream>>>(x0, wim + (size_t)1024 * 32, nbuf);
  k_recur<<<64, 1024, 0, stream>>>(nbuf, whm + (size_t)1024 * 32, bih, bhh, flags, 1,
                                   (unsigned long long*)0, hidm + 64 * 32);
  k_fc<<<128, 64, 0, stream>>>(hidm, fcm, flags, d_out);
}

// Round 7
// 2332.006 us; speedup vs baseline: 21.6625x; 1.0438x over previous
//
#include <hip/hip_runtime.h>
#include <cstdint>
#include <cstddef>

// ---------------------------------------------------------------------------
// QRNN 2-bit forward, exact ternary-integer formulation.
// flags[0]=1 -> floats are f32 (else bf16); flags[1]=1 -> text is int64.
// Ternary vectors (len 1024) bit-packed as 32 u64: [2i]=plus, [2i+1]=nonzero.
// As uint4 i: (p.lo, p.hi, z.lo, z.hi) for elements 64i..64i+63.
// dot: both=hz&wz; neg=both&(hp^wp); k=popc(both)-2*popc(neg)
// Decision v = k*0.1+bias vs +-0.5 is monotone in k -> integer thresholds
// kp/km reproduce the f64 predicate bit-exactly.
//
// R7 k_recur: 256 threads/block (1 wave/SIMD, ~512-VGPR budget), 4 rows per
// thread -> weights stay in registers AND the h-broadcast LDS traffic drops
// 4x (64 ds_read_b128/step/CU). Single block-uniform empty-h skip (scalar
// branch on a packed flag word) -- NO per-word branches (R6 regression:
// they serialized the dense path). ~2/3 of batches have h == 0 forever
// (P(any |b_ih+b_hh|>0.5 row) ~ 0.33) and take the fast path; dense
// (avalanched) blocks run a straight-line 640-VALU dot.
// ---------------------------------------------------------------------------

static __device__ __forceinline__ float bf2f(unsigned short b) {
  return __uint_as_float(((unsigned)b) << 16);
}
static __device__ __forceinline__ unsigned short f2bf(float f) {
  unsigned u = __float_as_uint(f);
  u = (u + 0x7FFFu + ((u >> 16) & 1u)) >> 16;  // RNE
  return (unsigned short)u;
}
static __device__ __forceinline__ float loadw(const void* p, size_t i, int isf32) {
  return isf32 ? ((const float*)p)[i] : bf2f(((const unsigned short*)p)[i]);
}

__global__ __launch_bounds__(256) void k_detect(const unsigned short* __restrict__ embu,
                                                const int* __restrict__ text,
                                                int* __restrict__ flags) {
  int i = blockIdx.x * 256 + threadIdx.x;  // 65536 u16 samples: valid in either layout
  unsigned e = (embu[i] >> 7) & 0xFFu;     // bf16-view exponent field
  unsigned long long b = __ballot(e >= 127u);
  if ((threadIdx.x & 63) == 0 && b) atomicOr(&flags[0], 1);
  if (blockIdx.x == 0 && threadIdx.x == 0) {
    int allz = 1;
    for (int j = 0; j < 32; j++)
      if (text[2 * j + 1] != 0) allz = 0;   // first 256 B: valid in either layout
    flags[1] = allz;
  }
}

__global__ __launch_bounds__(256) void k_maxabs(const uint4* __restrict__ w,
                                                const int* __restrict__ flags,
                                                unsigned* __restrict__ out) {
  int isf32 = flags[0];
  int n16 = isf32 ? 7680000 : 3840000;  // 30720000 elems / (4 or 8 per uint4)
  float mf = 0.f;
  unsigned mb = 0;
  int i = blockIdx.x * blockDim.x + threadIdx.x;
  int stride = gridDim.x * blockDim.x;
  if (isf32) {
    for (; i < n16; i += stride) {
      uint4 v = w[i];
      mf = fmaxf(mf, fabsf(__uint_as_float(v.x)));
      mf = fmaxf(mf, fabsf(__uint_as_float(v.y)));
      mf = fmaxf(mf, fabsf(__uint_as_float(v.z)));
      mf = fmaxf(mf, fabsf(__uint_as_float(v.w)));
    }
  } else {
    for (; i < n16; i += stride) {
      uint4 v = w[i];
      unsigned a;
      a = v.x & 0x7FFF7FFFu; mb = max(mb, a & 0xFFFFu); mb = max(mb, a >> 16);
      a = v.y & 0x7FFF7FFFu; mb = max(mb, a & 0xFFFFu); mb = max(mb, a >> 16);
      a = v.z & 0x7FFF7FFFu; mb = max(mb, a & 0xFFFFu); mb = max(mb, a >> 16);
      a = v.w & 0x7FFF7FFFu; mb = max(mb, a & 0xFFFFu); mb = max(mb, a >> 16);
    }
    mf = bf2f((unsigned short)mb);
  }
  for (int off = 32; off > 0; off >>= 1) mf = fmaxf(mf, __shfl_down(mf, off));
  __shared__ float red[4];
  if ((threadIdx.x & 63) == 0) red[threadIdx.x >> 6] = mf;
  __syncthreads();
  if (threadIdx.x == 0) {
    float b = fmaxf(fmaxf(red[0], red[1]), fmaxf(red[2], red[3]));
    atomicMax(out, __float_as_uint(b));  // b >= 0: bit pattern order-monotone
  }
}

__global__ __launch_bounds__(1024) void k_tern_rows(
    const void* __restrict__ Wih, const void* __restrict__ Whh,
    const void* __restrict__ fcw, const int* __restrict__ flags,
    unsigned long long* __restrict__ wim, unsigned long long* __restrict__ whm,
    unsigned long long* __restrict__ fcm) {
  int isf32 = flags[0];
  int b = blockIdx.x;  // 0..4099
  const void* src;
  size_t rowoff;
  unsigned long long* dst;
  if (b < 2048)      { src = Wih; rowoff = (size_t)b * 1024; dst = wim + (size_t)b * 32; }
  else if (b < 4096) { int r = b - 2048; src = Whh; rowoff = (size_t)r * 1024; dst = whm + (size_t)r * 32; }
  else               { int r = b - 4096; src = fcw; rowoff = (size_t)r * 1024; dst = fcm + (size_t)r * 32; }
  double w = (double)loadw(src, rowoff + threadIdx.x, isf32);
  unsigned long long bp = __ballot(w > 0.05);   // THR*W_SCALE, exact f64
  unsigned long long bm = __ballot(w < -0.05);
  if ((threadIdx.x & 63) == 0) {
    int wv = threadIdx.x >> 6;
    dst[2 * wv] = bp;
    dst[2 * wv + 1] = bp | bm;
  }
}

__global__ __launch_bounds__(1024) void k_embed(const int* __restrict__ text,
    const void* __restrict__ emb, const int* __restrict__ flags,
    const unsigned* __restrict__ mab, unsigned long long* __restrict__ x0) {
  int isf32 = flags[0], i64 = flags[1];
  int bt = blockIdx.x;
  long long tok = i64 ? ((const long long*)text)[bt] : (long long)text[bt];
  double ma = (double)__uint_as_float(*mab);
  float s = (float)exp2(ceil(log2(ma)));           // pow-2 scale (int_max = 1)
  float inv_s = 1.0f / s;                          // exact (pow-2)
  float w = loadw(emb, (size_t)tok * 1024 + threadIdx.x, isf32);
  float q = rintf(w * inv_s);                      // exact mul, half-even
  q = fminf(fmaxf(q, -2.0f), 1.0f);                // clip [-2, 1] (bw = 2)
  float val = q * s;                               // exact
  int code = (val > 0.5f) ? 1 : ((val < -0.5f) ? -1 : 0);
  unsigned long long bp = __ballot(code == 1);
  unsigned long long bm = __ballot(code == -1);
  if ((threadIdx.x & 63) == 0) {
    int wv = threadIdx.x >> 6;
    x0[(size_t)bt * 32 + 2 * wv] = bp;
    x0[(size_t)bt * 32 + 2 * wv + 1] = bp | bm;
  }
}

// ---- bit-GEMM: n[bt][r] = <x_row[bt], Wi_row[r]> (integer) ----------------
// R4 form: row-level `any` skip only, unguarded batched word loop.
__global__ __launch_bounds__(256, 4) void k_bitgemm(const unsigned long long* __restrict__ xm,
    const unsigned long long* __restrict__ wim, short* __restrict__ nbuf) {
  __shared__ __align__(16) uint4 lx[64 * 16];  // [bt][i] = (p.lo,p.hi,z.lo,z.hi)
  __shared__ unsigned any[64];
  int tid = threadIdx.x;
  int bt0 = blockIdx.x * 64;
  int r = blockIdx.y * 256 + tid;
  unsigned wplo[16], wphi[16], wzlo[16], wzhi[16];
  const uint4* wrow = (const uint4*)(wim + (size_t)r * 32);
#pragma unroll
  for (int i = 0; i < 16; i++) {
    uint4 w4 = wrow[i];
    wplo[i] = w4.x; wphi[i] = w4.y; wzlo[i] = w4.z; wzhi[i] = w4.w;
  }
  if (tid < 64) any[tid] = 0;
  __syncthreads();
  unsigned accor = 0;
#pragma unroll
  for (int i = 0; i < 4; i++) {
    int idx = tid * 4 + i;  // 0..1023 uint4 slots, straight copy
    uint4 v = ((const uint4*)(xm + (size_t)bt0 * 32))[idx];
    lx[idx] = v;
    accor |= v.z | v.w;  // nonzero-mask halves
  }
  if (accor) atomicOr(&any[tid >> 2], 1u);  // 4 threads per bt row
  __syncthreads();
  for (int bt = 0; bt < 64; bt++) {
    int k = 0;
    if (any[bt]) {
      const uint4* hx = lx + bt * 16;
      int sb = 0, sn = 0;
#pragma unroll
      for (int i = 0; i < 16; i++) {
        uint4 h = hx[i];  // broadcast ds_read_b128, batched
        unsigned blo = h.z & wzlo[i];
        unsigned bhi = h.w & wzhi[i];
        unsigned nlo = (h.x ^ wplo[i]) & blo;
        unsigned nhi = (h.y ^ wphi[i]) & bhi;
        sb += __popc(blo) + __popc(bhi);
        sn += __popc(nlo) + __popc(nhi);
      }
      k = sb - 2 * sn;
    }
    nbuf[(size_t)(bt0 + bt) * 1024 + r] = (short)k;
  }
}

// ---- persistent recurrence: 256 threads, 4 rows/thread --------------------
// Thread u (wave W = u>>6, lane = u&63) owns rows u+256j, j=0..3.
// Ballot of row-group j in wave W covers rows 256j+64W.. -> h-word 4j+W.
__global__ __launch_bounds__(256, 1) void k_recur(const short* __restrict__ nbuf,
    const unsigned long long* __restrict__ whm,
    const void* __restrict__ bih, const void* __restrict__ bhh,
    const int* __restrict__ flags, int layer,
    unsigned long long* __restrict__ xout, unsigned long long* __restrict__ hidm) {
  int isf32 = flags[0];
  int b = blockIdx.x, u = threadIdx.x;
  int W = u >> 6, lane = u & 63;
  unsigned wplo[4][16], wphi[4][16], wzlo[4][16], wzhi[4][16];  // 256 VGPRs
#pragma unroll
  for (int j = 0; j < 4; j++) {
    const uint4* wrow = (const uint4*)(whm + (size_t)(u + 256 * j) * 32);
#pragma unroll
    for (int i = 0; i < 16; i++) {
      uint4 w4 = wrow[i];
      wplo[j][i] = w4.x; wphi[j][i] = w4.y; wzlo[j][i] = w4.z; wzhi[j][i] = w4.w;
    }
  }
  int kp[4], km[4];
#pragma unroll
  for (int j = 0; j < 4; j++) {
    size_t boff = (size_t)layer * 1024 + u + 256 * j;
    double bias = (double)loadw(bih, boff, isf32) + (double)loadw(bhh, boff, isf32);
    int a = (int)ceil((0.5 - bias) * 10.0);
    while ((double)a * 0.1 + bias <= 0.5) a++;
    while ((double)(a - 1) * 0.1 + bias > 0.5) a--;
    kp[j] = a;
    int c = (int)floor((-0.5 - bias) * 10.0);
    while ((double)c * 0.1 + bias >= -0.5) c--;
    while ((double)(c + 1) * 0.1 + bias < -0.5) c++;
    km[j] = c;
  }

  __shared__ __align__(16) uint4 Hbuf[2][16];
  __shared__ unsigned nzu[2];  // byte W = (wave W's 4 words nonzero)
  if (u < 32) ((unsigned long long*)Hbuf)[u] = 0;  // zero parity-0 H
  if (u < 2) nzu[u] = 0;
  __syncthreads();

  const short* nrow = nbuf + (size_t)b * 512 * 1024 + u;
  unsigned long long* xrow = xout ? xout + (size_t)b * 512 * 32 : (unsigned long long*)0;
  int nin[4];
#pragma unroll
  for (int j = 0; j < 4; j++) nin[j] = (int)nrow[256 * j];  // t = 0 preload
  int pb = 0;
  unsigned long long bp[4], bz[4];
  for (int t = 0; t < 512; t++) {
    unsigned flu = (unsigned)__builtin_amdgcn_readfirstlane((int)nzu[pb]);
    int nxt[4];
    if (t < 511) {  // prefetch early: covered by the dot below
#pragma unroll
      for (int j = 0; j < 4; j++) nxt[j] = (int)nrow[(size_t)(t + 1) * 1024 + 256 * j];
    } else {
#pragma unroll
      for (int j = 0; j < 4; j++) nxt[j] = 0;
    }
    int k[4];
#pragma unroll
    for (int j = 0; j < 4; j++) k[j] = nin[j];
    if (flu) {  // block-uniform scalar branch; batched loads + straight-line dot
      uint4 h[16];
      const uint4* Hq = Hbuf[pb];
#pragma unroll
      for (int i = 0; i < 16; i++) h[i] = Hq[i];  // 16 broadcast ds_read_b128
#pragma unroll
      for (int j = 0; j < 4; j++) {
        int sb = 0, sn = 0;
#pragma unroll
        for (int i = 0; i < 16; i++) {
          unsigned blo = h[i].z & wzlo[j][i];
          unsigned bhi = h[i].w & wzhi[j][i];
          unsigned nlo = (h[i].x ^ wplo[j][i]) & blo;
          unsigned nhi = (h[i].y ^ wphi[j][i]) & bhi;
          sb += __popc(blo) + __popc(bhi);
          sn += __popc(nlo) + __popc(nhi);
        }
        k[j] += sb - 2 * sn;
      }
    }
    unsigned anynz = 0;
#pragma unroll
    for (int j = 0; j < 4; j++) {
      bp[j] = __ballot(k[j] >= kp[j]);
      bz[j] = bp[j] | __ballot(k[j] <= km[j]);
      anynz |= (unsigned)(bz[j] | (bz[j] >> 32));
    }
    int np = pb ^ 1;
    if (lane == 0) {
#pragma unroll
      for (int j = 0; j < 4; j++) {
        uint4 o;
        o.x = (unsigned)bp[j]; o.y = (unsigned)(bp[j] >> 32);
        o.z = (unsigned)bz[j]; o.w = (unsigned)(bz[j] >> 32);
        Hbuf[np][4 * j + W] = o;
        if (xrow) ((uint4*)(xrow + (size_t)t * 32))[4 * j + W] = o;
      }
      ((unsigned char*)&nzu[np])[W] = anynz ? 1u : 0u;
    }
    __syncthreads();  // writes of parity np visible; reads of parity pb done
    pb = np;
#pragma unroll
    for (int j = 0; j < 4; j++) nin[j] = nxt[j];
  }
  if (lane == 0) {  // final h
#pragma unroll
    for (int j = 0; j < 4; j++) {
      hidm[b * 32 + 2 * (4 * j + W)] = bp[j];
      hidm[b * 32 + 2 * (4 * j + W) + 1] = bz[j];
    }
  }
}

__global__ __launch_bounds__(64) void k_fc(const unsigned long long* __restrict__ hidm,
    const unsigned long long* __restrict__ fcm, const int* __restrict__ flags,
    void* __restrict__ out) {
  int isf32 = flags[0];
  int lb = blockIdx.x, lane = threadIdx.x;
  unsigned long long hp = 0, hz = 0;
  if (lane < 16) {
    hp = hidm[lb * 32 + 2 * lane];
    hz = hidm[lb * 32 + 2 * lane + 1];
  }
#pragma unroll
  for (int o = 0; o < 4; o++) {
    int k = 0;
    if (lane < 16) {
      unsigned long long wp = fcm[o * 32 + 2 * lane], wz = fcm[o * 32 + 2 * lane + 1];
      unsigned long long both = hz & wz;
      unsigned long long neg = both & (hp ^ wp);
      k = __popcll(both) - 2 * __popcll(neg);
    }
    for (int off = 8; off > 0; off >>= 1) k += __shfl_down(k, off);
    if (lane == 0) {
      float v = (float)((double)k * 0.1);
      if (isf32) ((float*)out)[lb * 4 + o] = v;
      else       ((unsigned short*)out)[lb * 4 + o] = f2bf(v);
    }
  }
}

extern "C" void kernel_launch(void* const* d_in, const int* in_sizes, int n_in,
                              void* d_out, int out_size, void* d_ws, size_t ws_size,
                              hipStream_t stream) {
  (void)in_sizes; (void)n_in; (void)out_size; (void)ws_size;
  const int* text = (const int*)d_in[0];
  // d_in[1] text_lengths: unused by the reference
  const void* emb = d_in[2];
  const void* Wih = d_in[3];
  const void* Whh = d_in[4];
  const void* bih = d_in[5];
  const void* bhh = d_in[6];
  const void* fcw = d_in[7];

  // workspace layout (~73 MB)
  char* ws = (char*)d_ws;
  size_t off = 0;
  int* flags = (int*)(ws);
  unsigned* mab = (unsigned*)(ws + 64);                      off += 256;
  unsigned long long* x0 = (unsigned long long*)(ws + off);  off += (size_t)32768 * 256;
  unsigned long long* wim = (unsigned long long*)(ws + off); off += (size_t)2048 * 256;
  unsigned long long* whm = (unsigned long long*)(ws + off); off += (size_t)2048 * 256;
  unsigned long long* fcm = (unsigned long long*)(ws + off); off += (size_t)4 * 256;
  unsigned long long* hidm = (unsigned long long*)(ws + off); off += (size_t)128 * 256;
  short* nbuf = (short*)(ws + off);                          off += (size_t)32768 * 1024 * 2;

  hipMemsetAsync(ws, 0, 256, stream);
  k_detect<<<256, 256, 0, stream>>>((const unsigned short*)emb, text, flags);
  k_maxabs<<<2048, 256, 0, stream>>>((const uint4*)emb, flags, mab);
  k_tern_rows<<<4100, 1024, 0, stream>>>(Wih, Whh, fcw, flags, wim, whm, fcm);
  k_embed<<<32768, 1024, 0, stream>>>(text, emb, flags, mab, x0);
  // layer 0: x0 -> nbuf -> recurrence -> x0 (x0 dead after bitgemm)
  k_bitgemm<<<dim3(512, 4), 256, 0, stream>>>(x0, wim, nbuf);
  k_recur<<<64, 256, 0, stream>>>(nbuf, whm, bih, bhh, flags, 0, x0, hidm);
  // layer 1
  k_bitgemm<<<dim3(512, 4), 256, 0, stream>>>(x0, wim + (size_t)1024 * 32, nbuf);
  k_recur<<<64, 256, 0, stream>>>(nbuf, whm + (size_t)1024 * 32, bih, bhh, flags, 1,
                                  (unsigned long long*)0, hidm + 64 * 32);
  k_fc<<<128, 64, 0, stream>>>(hidm, fcm, flags, d_out);
}